// Round 1
// baseline (242.734 us; speedup 1.0000x reference)
//
#include <hip/hip_runtime.h>

#define NKEYS 8
#define MAXLEN 200
#define TBL_SZ (NKEYS * MAXLEN)   // 1600 floats = 6.4 KB LDS
#define BLOCK 256

__global__ __launch_bounds__(BLOCK) void pw_gather_kernel(
    const float* __restrict__ pw,      // [F*L] position weight table
    const int*   __restrict__ keys,    // [n] key ids
    const int*   __restrict__ poss,    // [n] positions
    float*       __restrict__ out,     // [n]
    int n)
{
    __shared__ float tbl[TBL_SZ];
    for (int i = threadIdx.x; i < TBL_SZ; i += BLOCK) {
        tbl[i] = pw[i];
    }
    __syncthreads();

    int idx = blockIdx.x * BLOCK + threadIdx.x;   // one thread = 4 elements
    long base = (long)idx * 4;
    if (base + 3 < n) {
        // vector path: 16B loads of both index streams, 16B store
        int4 k = ((const int4*)keys)[idx];
        int4 p = ((const int4*)poss)[idx];
        float4 o;
        o.x = tbl[k.x * MAXLEN + p.x];
        o.y = tbl[k.y * MAXLEN + p.y];
        o.z = tbl[k.z * MAXLEN + p.z];
        o.w = tbl[k.w * MAXLEN + p.w];
        ((float4*)out)[idx] = o;
    } else {
        // scalar tail (dead for n % 4 == 0, kept for generality)
        for (long j = base; j < n; ++j) {
            out[j] = tbl[keys[j] * MAXLEN + poss[j]];
        }
    }
}

extern "C" void kernel_launch(void* const* d_in, const int* in_sizes, int n_in,
                              void* d_out, int out_size, void* d_ws, size_t ws_size,
                              hipStream_t stream) {
    const float* pw   = (const float*)d_in[0];
    const int*   keys = (const int*)d_in[1];
    const int*   poss = (const int*)d_in[2];
    float*       out  = (float*)d_out;

    int n  = in_sizes[1];              // total jagged values T
    int n4 = (n + 3) / 4;              // elements per thread = 4
    int blocks = (n4 + BLOCK - 1) / BLOCK;

    pw_gather_kernel<<<blocks, BLOCK, 0, stream>>>(pw, keys, poss, out, n);
}